// Round 1
// 240.943 us; speedup vs baseline: 1.0149x; 1.0149x over previous
//
#include <hip/hip_runtime.h>
#include <math.h>

// DivMergedLayer1: reference collapses to out = x except 4 floats per row.
//   N=32, D=128, F=4096, B=8192. Flat row layout: x[b, n, d] -> xr[n*128 + d].
//   op  = xr[67]            (OP_START+OPCODE = 64+3, nibble row 0)
//   r60 = relu(60*op); inv60 = fp32(1/60)
//   P   = sum_{i=0..31} 2^i * xr[i*128 + 0]     (gate reads NIB_A = col 0)
//   softmax path (NIB_B = col 1), ALGEBRAICALLY SIMPLIFIED:
//     reference: score_i = d_i>0.5 ? log(max(d_i*2^i,0.5)) : -60
//                recip   = exp(-mx)/sum exp(score_i-mx)  ==  1/sum_i exp(score_i)
//     so directly: t_i = d_i>0.5 ? max(d_i*2^i, 0.5) : exp(-60)
//                  recip = 1/sum_i t_i            (no log/exp needed at all;
//     sum >= 32*exp(-60) > 0 so the ref's 1e-30 clamp never binds)
//   out[2] = x2 + (dc2 + dg2); out[3] = x3 + dc3; out[4] likewise
//   out[5] = (x5 + dc5) + op*(float)recip;  everything else = x exactly.
//
// Memory-bound: 128 MiB in + 128 MiB out -> ~42 us roofline at 6.3 TB/s.
// Structural change vs previous version: no scattered gather, no f64 log/exp.
// The streaming loop itself supplies the reduction inputs: float4 index 32n
// (loaded by threads with t%32==0) carries cols 0,1 of nibble row n; those
// threads stash (a,d) into LDS while the copy streams. One barrier; wave 0
// lanes 0..31 do a 5-stage f64 butterfly; threads 0 and 1 store the two
// patched float4s at the end. All other stores are issued before the barrier.

#define FDIM 4096

__global__ __launch_bounds__(256) void div_merged_kernel(
    const float* __restrict__ x, float* __restrict__ out) {
  const long long row = blockIdx.x;
  const float4* __restrict__ x4 = (const float4*)(x + row * (long long)FDIM);
  float4* __restrict__ o4 = (float4*)(out + row * (long long)FDIM);
  const int t = threadIdx.x;

  __shared__ float sa[32];  // xr[n*128 + 0]  (NIB_A)
  __shared__ float sd[32];  // xr[n*128 + 1]  (NIB_B)

  // Issue all 4 streaming loads up front (1024 float4 per row).
  float4 v0 = x4[t];
  float4 v1 = x4[t + 256];
  float4 v2 = x4[t + 512];
  float4 v3 = x4[t + 768];

  // float4 index 32n holds flat floats {128n .. 128n+3}: .x = NIB_A, .y = NIB_B.
  // idx = t + 256k with t%32==0  ->  n = 8k + t/32; k=0..3 covers n = 0..31.
  if ((t & 31) == 0) {
    const int n0 = t >> 5;  // 0..7
    sa[n0]      = v0.x;  sd[n0]      = v0.y;
    sa[n0 + 8]  = v1.x;  sd[n0 + 8]  = v1.y;
    sa[n0 + 16] = v2.x;  sd[n0 + 16] = v2.y;
    sa[n0 + 24] = v3.x;  sd[n0 + 24] = v3.y;
  }

  // Stream everything out except float4 0 and 1 (the 8 floats containing
  // flat indices 2..5, patched after the reduction).
  if (t >= 2) o4[t] = v0;
  o4[t + 256] = v1;
  o4[t + 512] = v2;
  o4[t + 768] = v3;

  __syncthreads();

  if (t < 32) {
    // op = xr[67] = thread 16's v0.w (float4 16 = floats 64..67).
    const float op = __shfl(v0.w, 16);

    const double pw = (double)(1ULL << t);  // 2^t, exact
    const double a  = (double)sa[t];
    const double d  = (double)sd[t];
    double p  = a * pw;                                    // gate-sum term
    double ts = (d > 0.5) ? fmax(d * pw, 0.5)
                          : 8.75651076269652e-27;          // exp(-60.0)
#pragma unroll
    for (int off = 1; off < 32; off <<= 1) {               // 5-stage butterfly
      p  += __shfl_xor(p, off);
      ts += __shfl_xor(ts, off);
    }
    // every lane 0..31 now holds the full sums
    const float r60   = fmaxf(60.0f * op, 0.0f);
    const float inv60 = (float)(1.0 / 60.0);
    const float Pf    = (float)p;
    const float recip = (float)(1.0 / ts);

    if (t == 0) {
      // v0 = flat floats 0..3: patch .z (flat 2) and .w (flat 3)
      const float x2v = v0.z, x3v = v0.w;
      const float dc2 = -((r60 * x2v) * inv60);
      const float dc3 = -((r60 * x3v) * inv60);
      const float dg2 = (r60 * Pf) * inv60;
      v0.z = x2v + (dc2 + dg2);
      v0.w = x3v + dc3;
      o4[0] = v0;
    } else if (t == 1) {
      // v0 = flat floats 4..7: patch .x (flat 4) and .y (flat 5)
      const float x4v = v0.x, x5v = v0.y;
      const float dc4 = -((r60 * x4v) * inv60);
      const float dc5 = -((r60 * x5v) * inv60);
      v0.x = x4v + dc4;
      v0.y = (x5v + dc5) + op * recip;
      o4[1] = v0;
    }
  }
}

extern "C" void kernel_launch(void* const* d_in, const int* in_sizes, int n_in,
                              void* d_out, int out_size, void* d_ws, size_t ws_size,
                              hipStream_t stream) {
  const float* x = (const float*)d_in[0];  // (B, 32, 128) fp32
  float* out = (float*)d_out;              // (B, 32, 128) fp32
  const int rows = in_sizes[0] / FDIM;     // B = 8192
  div_merged_kernel<<<rows, 256, 0, stream>>>(x, out);
}

// Round 3
// 236.395 us; speedup vs baseline: 1.0344x; 1.0192x over previous
//
#include <hip/hip_runtime.h>
#include <math.h>

// DivMergedLayer1: reference collapses to out = x except 4 floats per row.
//   N=32, D=128, F=4096, B=8192. Flat row layout: x[b, n, d] -> xr[n*128 + d].
//   op  = xr[67]            (OP_START+OPCODE = 64+3, nibble row 0)
//   r60 = relu(60*op); inv60 = fp32(1/60)
//   P   = sum_{i=0..31} 2^i * xr[i*128 + 0]     (gate reads NIB_A = col 0)
//   softmax path (NIB_B = col 1), algebraically simplified:
//     recip = exp(-mx)/sum exp(score_i-mx) == 1/sum_i exp(score_i)
//     t_i = d_i>0.5 ? max(d_i*2^i, 0.5) : exp(-60);  recip = 1/sum t_i
//     (sum >= 32*exp(-60) > 0, so the ref's 1e-30 clamp never binds)
//   out[2] = x2 + (dc2 + dg2); out[3] = x3 + dc3; out[4] likewise
//   out[5] = (x5 + dc5) + op*(float)recip;  everything else = x exactly.
//
// Memory-bound: 128 MiB in + 128 MiB out -> ~42 us roofline at 6.3 TB/s.
//
// Structure: ONE WAVE PER ROW. Block = 4 waves = 4 rows, grid = 2048.
// Each lane holds 16 float4 (row = 1024 float4 = 64 lanes x 16). The nibble
// quads (float4 index 32n) live at reg k=n>>1 in lanes 0 (n even) and 32
// (n odd) -- so the reduction is register-local with compile-time weights
// 4^k * (lane>=32 ? 2 : 1); lanes other than 0/32 compute garbage that is
// discarded. ONE __shfl_xor(32) combines halves, two __shfl broadcast.
// No LDS, no __syncthreads -> no per-block s_waitcnt vmcnt(0) drain; the
// wave keeps 16 loads in flight and streams stores straight out.
// Nontemporal loads: input is never re-read, keep it out of L2/L3.
// (nontemporal builtin needs a clang ext_vector_type pointer, not
//  HIP_vector_type -- hence vf4 below.)

#define FDIM 4096
#define ROWS_PER_BLOCK 4

typedef float vf4 __attribute__((ext_vector_type(4)));

__global__ __launch_bounds__(256) void div_merged_kernel(
    const float* __restrict__ x, float* __restrict__ out, int rows) {
  const int t = threadIdx.x;
  const int wave = t >> 6;
  const int lane = t & 63;
  const long long row = (long long)blockIdx.x * ROWS_PER_BLOCK + wave;
  if (row >= rows) return;

  const vf4* __restrict__ x4 = (const vf4*)(x + row * (long long)FDIM);
  vf4* __restrict__ o4 = (vf4*)(out + row * (long long)FDIM);

  // Load the whole row: reg k <- float4[k*64 + lane] (1 KiB/instr, coalesced).
  vf4 v[16];
#pragma unroll
  for (int k = 0; k < 16; ++k)
    v[k] = __builtin_nontemporal_load(&x4[k * 64 + lane]);

  // ---- wave-local reduction (meaningful only on lanes 0 and 32) ----
  // lane 0 holds nibble rows n=2k in v[k].{x,y}; lane 32 holds n=2k+1.
  // weight for v[k] on this lane: 2^n = 4^k * (lane>=32 ? 2 : 1).
  const double base2 = (lane >= 32) ? 2.0 : 1.0;
  double p = 0.0, ts = 0.0;
#pragma unroll
  for (int k = 0; k < 16; ++k) {
    const double wk = base2 * (double)(1ULL << (2 * k));  // compile-time 4^k
    p += (double)v[k].x * wk;                             // gate-sum term
    const double d = (double)v[k].y;
    ts += (d > 0.5) ? fmax(d * wk, 0.5)
                    : 8.75651076269652e-27;               // exp(-60.0)
  }
  // combine even (lane 0) and odd (lane 32) halves, then broadcast.
  p  += __shfl_xor(p, 32);
  ts += __shfl_xor(ts, 32);
  p  = __shfl(p, 0);
  ts = __shfl(ts, 0);
  // op = xr[67]: float4 index 16 = (k=0, lane=16), component .w.
  const float op = __shfl(v[0].w, 16);

  const float r60   = fmaxf(60.0f * op, 0.0f);
  const float inv60 = (float)(1.0 / 60.0);
  const float Pf    = (float)p;
  const float recip = (float)(1.0 / ts);

  if (lane == 0) {
    // v[0] = flats 0..3: patch .z (flat 2) and .w (flat 3)
    const float x2v = v[0].z, x3v = v[0].w;
    const float dc2 = -((r60 * x2v) * inv60);
    const float dc3 = -((r60 * x3v) * inv60);
    const float dg2 = (r60 * Pf) * inv60;
    v[0].z = x2v + (dc2 + dg2);
    v[0].w = x3v + dc3;
  } else if (lane == 1) {
    // v[0] = flats 4..7: patch .x (flat 4) and .y (flat 5)
    const float x4v = v[0].x, x5v = v[0].y;
    const float dc4 = -((r60 * x4v) * inv60);
    const float dc5 = -((r60 * x5v) * inv60);
    v[0].x = x4v + dc4;
    v[0].y = (x5v + dc5) + op * recip;
  }

  // Stream the row out.
#pragma unroll
  for (int k = 0; k < 16; ++k)
    o4[k * 64 + lane] = v[k];
}

extern "C" void kernel_launch(void* const* d_in, const int* in_sizes, int n_in,
                              void* d_out, int out_size, void* d_ws, size_t ws_size,
                              hipStream_t stream) {
  const float* x = (const float*)d_in[0];  // (B, 32, 128) fp32
  float* out = (float*)d_out;              // (B, 32, 128) fp32
  const int rows = in_sizes[0] / FDIM;     // B = 8192
  const int blocks = (rows + ROWS_PER_BLOCK - 1) / ROWS_PER_BLOCK;
  div_merged_kernel<<<blocks, 256, 0, stream>>>(x, out, rows);
}

// Round 5
// 235.908 us; speedup vs baseline: 1.0366x; 1.0021x over previous
//
#include <hip/hip_runtime.h>
#include <math.h>

// DivMergedLayer1: reference collapses to out = x except 4 floats per row.
//   N=32, D=128, F=4096, B=8192. Flat row layout: x[b, n, d] -> xr[n*128 + d].
//   op  = xr[67]            (OP_START+OPCODE = 64+3, nibble row 0)
//   r60 = relu(60*op); inv60 = fp32(1/60)
//   P   = sum_{i=0..31} 2^i * xr[i*128 + 0]     (gate reads NIB_A = col 0)
//   softmax path (NIB_B = col 1), algebraically simplified:
//     recip = exp(-mx)/sum exp(score_i-mx) == 1/sum_i exp(score_i)
//     t_i = d_i>0.5 ? max(d_i*2^i, 0.5) : exp(-60);  recip = 1/sum t_i
//     (sum >= 32*exp(-60) > 0, so the ref's 1e-30 clamp never binds)
//   out[2] = x2 + (dc2 + dg2); out[3] = x3 + dc3; out[4] likewise
//   out[5] = (x5 + dc5) + op*(float)recip;  everything else = x exactly.
//
// Memory-bound: 128 MiB in + 128 MiB out -> ~42 us roofline at 6.3 TB/s.
//
// Structure: ONE WAVE PER ROW (block = 4 waves = 4 rows, grid = 2048), no LDS,
// no __syncthreads. Round-4 change: process the row in TWO CHUNKS OF 8 float4
// with store-as-you-go -- each store issues as soon as its load returns,
// overlapping the store stream with the load-return tail instead of parking
// all 16 stores behind the reduction + shuffles + patch. Only v0 (flats 0..7
// on lanes 0/1) is held back for the patch. Peak live state drops from 16 to
// ~9 float4 -> lower VGPR, more waves/SIMD.
//
// Reduction layout: float4 index 32n lives at (k = n>>1, lane = 32*(n&1)),
// so lanes 0 / 32 hold nibble rows n even / odd in their own registers;
// weight for reg k is 4^k * (lane>=32 ? 2 : 1) -- compile-time. Other lanes
// compute garbage that is discarded. One __shfl_xor(32) combines halves.

#define FDIM 4096
#define ROWS_PER_BLOCK 4

typedef float vf4 __attribute__((ext_vector_type(4)));

__global__ __launch_bounds__(256) void div_merged_kernel(
    const float* __restrict__ x, float* __restrict__ out, int rows) {
  const int t = threadIdx.x;
  const int wave = t >> 6;
  const int lane = t & 63;
  const long long row = (long long)blockIdx.x * ROWS_PER_BLOCK + wave;
  if (row >= rows) return;

  const vf4* __restrict__ x4 = (const vf4*)(x + row * (long long)FDIM);
  vf4* __restrict__ o4 = (vf4*)(out + row * (long long)FDIM);

  const double base2 = (lane >= 32) ? 2.0 : 1.0;
  double p = 0.0, ts = 0.0;
  vf4 v[8];
  vf4 v0;

  // ---- chunk A: float4 k = 0..7 ----
#pragma unroll
  for (int k = 0; k < 8; ++k)
    v[k] = __builtin_nontemporal_load(&x4[k * 64 + lane]);
#pragma unroll
  for (int k = 0; k < 8; ++k) {
    const double wk = base2 * (double)(1ULL << (2 * k));  // 4^k, compile-time
    p += (double)v[k].x * wk;
    const double d = (double)v[k].y;
    ts += (d > 0.5) ? fmax(d * wk, 0.5)
                    : 8.75651076269652e-27;               // exp(-60.0)
    if (k == 0) v0 = v[0];                                // hold for patch
    else o4[k * 64 + lane] = v[k];                        // store as soon as ready
  }

  // ---- chunk B: float4 k = 8..15 ----
#pragma unroll
  for (int k = 0; k < 8; ++k)
    v[k] = __builtin_nontemporal_load(&x4[(k + 8) * 64 + lane]);
#pragma unroll
  for (int k = 0; k < 8; ++k) {
    const double wk = base2 * (double)(1ULL << (2 * k + 16));  // 4^(k+8)
    p += (double)v[k].x * wk;
    const double d = (double)v[k].y;
    ts += (d > 0.5) ? fmax(d * wk, 0.5)
                    : 8.75651076269652e-27;               // exp(-60.0)
    o4[(k + 8) * 64 + lane] = v[k];
  }

  // combine even (lane 0) and odd (lane 32) halves, then broadcast.
  p  += __shfl_xor(p, 32);
  ts += __shfl_xor(ts, 32);
  p  = __shfl(p, 0);
  ts = __shfl(ts, 0);
  // op = xr[67]: float4 16 = floats 64..67 = (k=0, lane=16) -> v0.w on lane 16.
  const float op = __shfl(v0.w, 16);

  const float r60   = fmaxf(60.0f * op, 0.0f);
  const float inv60 = (float)(1.0 / 60.0);
  const float Pf    = (float)p;
  const float recip = (float)(1.0 / ts);

  if (lane == 0) {
    // v0 = flats 0..3: patch .z (flat 2) and .w (flat 3)
    const float x2v = v0.z, x3v = v0.w;
    const float dc2 = -((r60 * x2v) * inv60);
    const float dc3 = -((r60 * x3v) * inv60);
    const float dg2 = (r60 * Pf) * inv60;
    v0.z = x2v + (dc2 + dg2);
    v0.w = x3v + dc3;
  } else if (lane == 1) {
    // v0 = flats 4..7: patch .x (flat 4) and .y (flat 5)
    const float x4v = v0.x, x5v = v0.y;
    const float dc4 = -((r60 * x4v) * inv60);
    const float dc5 = -((r60 * x5v) * inv60);
    v0.x = x4v + dc4;
    v0.y = (x5v + dc5) + op * recip;
  }

  // k=0 store: patched on lanes 0/1, pass-through elsewhere.
  o4[lane] = v0;
}

extern "C" void kernel_launch(void* const* d_in, const int* in_sizes, int n_in,
                              void* d_out, int out_size, void* d_ws, size_t ws_size,
                              hipStream_t stream) {
  const float* x = (const float*)d_in[0];  // (B, 32, 128) fp32
  float* out = (float*)d_out;              // (B, 32, 128) fp32
  const int rows = in_sizes[0] / FDIM;     // B = 8192
  const int blocks = (rows + ROWS_PER_BLOCK - 1) / ROWS_PER_BLOCK;
  div_merged_kernel<<<blocks, 256, 0, stream>>>(x, out, rows);
}